// Round 3
// baseline (748.420 us; speedup 1.0000x reference)
//
#include <hip/hip_runtime.h>

typedef __attribute__((ext_vector_type(8))) short short8;
typedef __attribute__((ext_vector_type(4))) float floatx4;

#define C_DIM 50000
#define D_DIM 1024
#define N_DIM 256
#define G_NUM 4
#define NNZ_G 300000
#define E_TOT (G_NUM * NNZ_G)

// workspace layout (bytes)
#define O_SB   0u
#define O_H0   8192u
#define O_ZT   532480u                 // Zt bf16 [50000][256] = 25600000
#define O_CNT  26132480u
#define O_OFF  26332544u
#define O_CUR  26532608u
#define O_BS   26732672u
#define O_EDG  26733696u               // edges int2[1200000]

static __device__ __forceinline__ unsigned short f2bf(float f) {
    union { float f; unsigned u; } v; v.f = f;
    unsigned r = v.u + 0x7fffu + ((v.u >> 16) & 1u);   // RNE
    return (unsigned short)(r >> 16);
}
static __device__ __forceinline__ float bf2f(unsigned short u) {
    union { unsigned u; float f; } v; v.u = ((unsigned)u) << 16;
    return v.f;
}
static __device__ __forceinline__ unsigned packbf(float a, float b) {
    return (unsigned)f2bf(a) | ((unsigned)f2bf(b) << 16);
}

// ---- 1. BatchNorm stats
__global__ __launch_bounds__(256) void k_bnstats(const float* __restrict__ x,
                                                 float* __restrict__ scale,
                                                 float* __restrict__ bias) {
    int d = blockIdx.x * 256 + threadIdx.x;
    float s = 0.f, ss = 0.f;
    for (int n = 0; n < N_DIM; ++n) {
        float v = x[n * D_DIM + d];
        s += v; ss += v * v;
    }
    float mean = s * (1.f / N_DIM);
    float var  = ss * (1.f / N_DIM) - mean * mean;
    float sc = rsqrtf(var + 1e-5f);
    scale[d] = sc;
    bias[d] = -mean * sc;
}

// ---- 2. h0 = normalize(x) in bf16
__global__ __launch_bounds__(256) void k_h0(const float* __restrict__ x,
                                            const float* __restrict__ scale,
                                            const float* __restrict__ bias,
                                            unsigned short* __restrict__ h0) {
    int id = blockIdx.x * 256 + threadIdx.x;
    int d = id & (D_DIM - 1);
    h0[id] = f2bf(x[id] * scale[d] + bias[d]);
}

// ---- 3. GEMM: Zt[c][b] = swish(W@h0 + wb). 64(C)x256(N)/block, W read once.
// Pipelined: W reg-prefetch -> convert -> dbuf LDS (1 barrier/step, BK=64).
// B (h0, L2-resident) fragments loaded DIRECTLY from global, no LDS.
#define AST 72          // As stride in shorts (144 B: b128-aligned, uniform banks)
__global__ __launch_bounds__(256, 3) void k_gemm(const float* __restrict__ W,
                                                 const float* __restrict__ wb,
                                                 const unsigned short* __restrict__ h0,
                                                 unsigned short* __restrict__ Zt) {
    __shared__ unsigned short As[2][64 * AST];
    const int t = threadIdx.x;
    const int c0 = blockIdx.x * 64;
    const int w = t >> 6, lane = t & 63;
    const int m = lane & 15, g = lane >> 4;
    const int arow = t >> 2, aseg = t & 3;      // staging: row 0..63, 16-k seg 0..3

    const int cA = c0 + arow;
    const bool aval = (cA < C_DIM);
    const float* wsrc = &W[(size_t)cA * D_DIM + aseg * 16];
    unsigned short* asdst0 = &As[0][arow * AST + aseg * 16];
    unsigned short* asdst1 = &As[1][arow * AST + aseg * 16];
    const unsigned short* bbase = h0 + ((w * 64 + m) * D_DIM + g * 8);

    floatx4 acc[4][4];
#pragma unroll
    for (int i = 0; i < 4; ++i)
#pragma unroll
        for (int j = 0; j < 4; ++j) acc[i][j] = (floatx4)0.f;

    float4 pf[4];
#pragma unroll
    for (int q = 0; q < 4; ++q)
        pf[q] = aval ? *(const float4*)(wsrc + q * 4) : make_float4(0.f, 0.f, 0.f, 0.f);
    // convert + store step 0
    {
        uint4 u0 = make_uint4(packbf(pf[0].x, pf[0].y), packbf(pf[0].z, pf[0].w),
                              packbf(pf[1].x, pf[1].y), packbf(pf[1].z, pf[1].w));
        uint4 u1 = make_uint4(packbf(pf[2].x, pf[2].y), packbf(pf[2].z, pf[2].w),
                              packbf(pf[3].x, pf[3].y), packbf(pf[3].z, pf[3].w));
        *(uint4*)asdst0 = u0; *(uint4*)(asdst0 + 8) = u1;
    }
    __syncthreads();

    for (int s = 0; s < 16; ++s) {
        // prefetch W chunk s+1 into regs (in flight during MFMA phase)
        if (s < 15 && aval) {
#pragma unroll
            for (int q = 0; q < 4; ++q)
                pf[q] = *(const float4*)(wsrc + (s + 1) * 64 + q * 4);
        }
        // MFMA phase on As[s&1]; B fragments straight from global h0
        const unsigned short* asrd = &As[s & 1][0];
#pragma unroll
        for (int ksub = 0; ksub < 2; ++ksub) {
            const unsigned short* bp = bbase + s * 64 + ksub * 32;
            short8 af[4], bfr[4];
#pragma unroll
            for (int j = 0; j < 4; ++j)
                bfr[j] = *(const short8*)(bp + j * 16 * D_DIM);
#pragma unroll
            for (int i = 0; i < 4; ++i)
                af[i] = *(const short8*)&asrd[(i * 16 + m) * AST + ksub * 32 + g * 8];
#pragma unroll
            for (int i = 0; i < 4; ++i)
#pragma unroll
                for (int j = 0; j < 4; ++j)
                    acc[i][j] = __builtin_amdgcn_mfma_f32_16x16x32_bf16(af[i], bfr[j], acc[i][j], 0, 0, 0);
        }
        if (s < 15) {
            unsigned short* dst = ((s + 1) & 1) ? asdst1 : asdst0;
            uint4 u0 = make_uint4(packbf(pf[0].x, pf[0].y), packbf(pf[0].z, pf[0].w),
                                  packbf(pf[1].x, pf[1].y), packbf(pf[1].z, pf[1].w));
            uint4 u1 = make_uint4(packbf(pf[2].x, pf[2].y), packbf(pf[2].z, pf[2].w),
                                  packbf(pf[3].x, pf[3].y), packbf(pf[3].z, pf[3].w));
            *(uint4*)dst = u0; *(uint4*)(dst + 8) = u1;
            __syncthreads();
        }
    }

    // epilogue: bias + swish, store bf16 to Zt[c][b] (write-merge verified OK)
#pragma unroll
    for (int i = 0; i < 4; ++i) {
#pragma unroll
        for (int j = 0; j < 4; ++j) {
            int b = w * 64 + j * 16 + m;
#pragma unroll
            for (int rr = 0; rr < 4; ++rr) {
                int c = c0 + i * 16 + g * 4 + rr;
                if (c < C_DIM) {
                    float x = acc[i][j][rr] + wb[c];
                    float z = x / (1.f + __expf(-x));
                    Zt[(size_t)c * 256 + b] = f2bf(z);
                }
            }
        }
    }
}

// ---- 4. CSR build
__global__ __launch_bounds__(256) void k_count(const int* __restrict__ rows,
                                               int* __restrict__ counts) {
    int id = blockIdx.x * 256 + threadIdx.x;
    if (id < E_TOT) atomicAdd(&counts[rows[id]], 1);
}

__global__ __launch_bounds__(256) void k_scan1(const int* __restrict__ counts,
                                               int* __restrict__ offsets,
                                               int* __restrict__ bsums) {
    __shared__ int sm[256];
    int t = threadIdx.x, i = blockIdx.x * 256 + t;
    int v = (i < C_DIM) ? counts[i] : 0;
    sm[t] = v; __syncthreads();
    for (int off = 1; off < 256; off <<= 1) {
        int x = (t >= off) ? sm[t - off] : 0;
        __syncthreads();
        sm[t] += x;
        __syncthreads();
    }
    if (i < C_DIM) offsets[i] = sm[t] - v;
    if (t == 255) bsums[blockIdx.x] = sm[255];
}

__global__ __launch_bounds__(256) void k_scan2(int* __restrict__ bsums,
                                               int* __restrict__ offsets) {
    __shared__ int sm[256];
    int t = threadIdx.x;
    int v = (t < 196) ? bsums[t] : 0;
    sm[t] = v; __syncthreads();
    for (int off = 1; off < 256; off <<= 1) {
        int x = (t >= off) ? sm[t - off] : 0;
        __syncthreads();
        sm[t] += x;
        __syncthreads();
    }
    if (t < 196) bsums[t] = sm[t] - v;
    if (t == 0) offsets[C_DIM] = sm[255];
}

__global__ __launch_bounds__(256) void k_scan3(const int* __restrict__ bsums,
                                               int* __restrict__ offsets,
                                               int* __restrict__ cursor) {
    int i = blockIdx.x * 256 + threadIdx.x;
    if (i < C_DIM) {
        int off = offsets[i] + bsums[blockIdx.x];
        offsets[i] = off;
        cursor[i] = off;
    }
}

__global__ __launch_bounds__(256) void k_scatter(const int* __restrict__ rows,
                                                 const int* __restrict__ cols,
                                                 const float* __restrict__ vals,
                                                 const float* __restrict__ vec,
                                                 int* __restrict__ cursor,
                                                 int2* __restrict__ edges) {
    int id = blockIdx.x * 256 + threadIdx.x;
    if (id < E_TOT) {
        int gidx = id / NNZ_G;
        float v = vals[id] * vec[gidx];
        int r = rows[id];
        int c = cols[id];
        int pos = atomicAdd(&cursor[r], 1);
        edges[pos] = make_int2(c, __float_as_int(v));
    }
}

// ---- 5. Aggregation + residual, XCD-panel-sliced.
// Panel p = batches [p*32, p*32+32); block bx&7 = p -> same XCD (round-robin
// dispatch heuristic): per-XCD gather working set = 50000*64 B = 3.2 MB < 4 MB L2.
// Wave = 1 row at a time, 8 edges/iter: lane = (edge slot 0..7) x (batch quad 0..7).
#define AGG_ROWS 64
__global__ __launch_bounds__(256, 8) void k_agg(const unsigned short* __restrict__ Zt,
                                                const int* __restrict__ offsets,
                                                const int2* __restrict__ edges,
                                                float* __restrict__ out) {
    __shared__ float sm[AGG_ROWS * 33];
    const int t = threadIdx.x, w = t >> 6, lane = t & 63;
    const int p = blockIdx.x & 7;
    const int r0 = (blockIdx.x >> 3) * AGG_ROWS;
    const int esub = lane >> 3;          // edge slot within 8-edge group
    const int bq = lane & 7;             // batch quad
    const int bOff = p * 32 + bq * 4;    // first of 4 batch columns (uint2 = 4 bf16)

#pragma unroll 1
    for (int k = 0; k < 16; ++k) {
        int lrow = w * 16 + k;
        int r = r0 + lrow;
        if (r >= C_DIM) break;           // wave-uniform
        int s = offsets[r], e = offsets[r + 1];
        float a0 = 0.f, a1 = 0.f, a2 = 0.f, a3 = 0.f;
        for (; s < e; s += 8) {
            int idx = s + esub;
            bool ok = idx < e;
            int2 ed = edges[ok ? idx : s];
            float v = ok ? __int_as_float(ed.y) : 0.f;
            uint2 gz = *(const uint2*)&Zt[(size_t)ed.x * 256 + bOff];
            a0 += v * bf2f((unsigned short)(gz.x & 0xffffu));
            a1 += v * bf2f((unsigned short)(gz.x >> 16));
            a2 += v * bf2f((unsigned short)(gz.y & 0xffffu));
            a3 += v * bf2f((unsigned short)(gz.y >> 16));
        }
        // butterfly-reduce across the 8 edge slots (lane stride 8)
#pragma unroll
        for (int d = 8; d < 64; d <<= 1) {
            a0 += __shfl_xor(a0, d, 64);
            a1 += __shfl_xor(a1, d, 64);
            a2 += __shfl_xor(a2, d, 64);
            a3 += __shfl_xor(a3, d, 64);
        }
        if (esub == 0) {
            uint2 rz = *(const uint2*)&Zt[(size_t)r * 256 + bOff];
            a0 += bf2f((unsigned short)(rz.x & 0xffffu));
            a1 += bf2f((unsigned short)(rz.x >> 16));
            a2 += bf2f((unsigned short)(rz.y & 0xffffu));
            a3 += bf2f((unsigned short)(rz.y >> 16));
            float* sp = &sm[lrow * 33 + bq * 4];
            sp[0] = a0; sp[1] = a1; sp[2] = a2; sp[3] = a3;
        }
    }
    __syncthreads();

    // coalesced write: 2 passes x float4; 16 consecutive lanes = 256 B contiguous
    const int rq = t & 15;               // row quad 0..15
    const int bl = t >> 4;               // 0..15
#pragma unroll
    for (int pass = 0; pass < 2; ++pass) {
        int b = p * 32 + pass * 16 + bl;
        int rbase = r0 + rq * 4;
        if (rbase + 3 < C_DIM) {
            float4 o;
            o.x = sm[(rq * 4 + 0) * 33 + pass * 16 + bl];
            o.y = sm[(rq * 4 + 1) * 33 + pass * 16 + bl];
            o.z = sm[(rq * 4 + 2) * 33 + pass * 16 + bl];
            o.w = sm[(rq * 4 + 3) * 33 + pass * 16 + bl];
            *(float4*)&out[(size_t)b * C_DIM + rbase] = o;
        }
    }
}

extern "C" void kernel_launch(void* const* d_in, const int* in_sizes, int n_in,
                              void* d_out, int out_size, void* d_ws, size_t ws_size,
                              hipStream_t stream) {
    (void)in_sizes; (void)n_in; (void)out_size; (void)ws_size;
    const float* x     = (const float*)d_in[0];
    const float* W     = (const float*)d_in[1];
    const float* wb    = (const float*)d_in[2];
    const float* Avals = (const float*)d_in[3];
    const float* vec   = (const float*)d_in[4];
    const int*   Arows = (const int*)d_in[5];
    const int*   Acols = (const int*)d_in[6];
    float* out = (float*)d_out;
    char* ws = (char*)d_ws;

    float* scale = (float*)(ws + O_SB);
    float* bias  = scale + 1024;
    unsigned short* h0 = (unsigned short*)(ws + O_H0);
    unsigned short* Zt = (unsigned short*)(ws + O_ZT);
    int* counts  = (int*)(ws + O_CNT);
    int* offsets = (int*)(ws + O_OFF);
    int* cursor  = (int*)(ws + O_CUR);
    int* bsums   = (int*)(ws + O_BS);
    int2* edges  = (int2*)(ws + O_EDG);

    hipMemsetAsync(counts, 0, C_DIM * sizeof(int), stream);

    k_bnstats<<<4, 256, 0, stream>>>(x, scale, bias);
    k_h0<<<1024, 256, 0, stream>>>(x, scale, bias, h0);
    k_count<<<(E_TOT + 255) / 256, 256, 0, stream>>>(Arows, counts);
    k_gemm<<<(C_DIM + 63) / 64, 256, 0, stream>>>(W, wb, h0, Zt);
    k_scan1<<<196, 256, 0, stream>>>(counts, offsets, bsums);
    k_scan2<<<1, 256, 0, stream>>>(bsums, offsets);
    k_scan3<<<196, 256, 0, stream>>>(bsums, offsets, cursor);
    k_scatter<<<(E_TOT + 255) / 256, 256, 0, stream>>>(Arows, Acols, Avals, vec, cursor, edges);
    k_agg<<<((C_DIM + AGG_ROWS - 1) / AGG_ROWS) * 8, 256, 0, stream>>>(Zt, offsets, edges, out);
}

// Round 4
// 679.143 us; speedup vs baseline: 1.1020x; 1.1020x over previous
//
#include <hip/hip_runtime.h>

typedef __attribute__((ext_vector_type(8))) short short8;
typedef __attribute__((ext_vector_type(4))) float floatx4;

#define C_DIM 50000
#define D_DIM 1024
#define N_DIM 256
#define G_NUM 4
#define NNZ_G 300000
#define E_TOT (G_NUM * NNZ_G)

// workspace layout (bytes)
#define O_SB   0u
#define O_H0   8192u
#define O_ZT   532480u                 // Zt bf16 [50000][256] = 25600000
#define O_CNT  26132480u
#define O_OFF  26332544u
#define O_CUR  26532608u
#define O_BS   26732672u
#define O_EDG  26733696u               // edges int2[1200000]

static __device__ __forceinline__ unsigned short f2bf(float f) {
    union { float f; unsigned u; } v; v.f = f;
    unsigned r = v.u + 0x7fffu + ((v.u >> 16) & 1u);   // RNE
    return (unsigned short)(r >> 16);
}
static __device__ __forceinline__ float bf2f(unsigned short u) {
    union { unsigned u; float f; } v; v.u = ((unsigned)u) << 16;
    return v.f;
}
static __device__ __forceinline__ unsigned packbf(float a, float b) {
    return (unsigned)f2bf(a) | ((unsigned)f2bf(b) << 16);
}
static __device__ __forceinline__ float bflo(unsigned u) {
    union { unsigned u; float f; } v; v.u = u << 16; return v.f;
}
static __device__ __forceinline__ float bfhi(unsigned u) {
    union { unsigned u; float f; } v; v.u = u & 0xffff0000u; return v.f;
}

// ---- 1. BatchNorm stats
__global__ __launch_bounds__(256) void k_bnstats(const float* __restrict__ x,
                                                 float* __restrict__ scale,
                                                 float* __restrict__ bias) {
    int d = blockIdx.x * 256 + threadIdx.x;
    float s = 0.f, ss = 0.f;
    for (int n = 0; n < N_DIM; ++n) {
        float v = x[n * D_DIM + d];
        s += v; ss += v * v;
    }
    float mean = s * (1.f / N_DIM);
    float var  = ss * (1.f / N_DIM) - mean * mean;
    float sc = rsqrtf(var + 1e-5f);
    scale[d] = sc;
    bias[d] = -mean * sc;
}

// ---- 2. h0 = normalize(x) in bf16
__global__ __launch_bounds__(256) void k_h0(const float* __restrict__ x,
                                            const float* __restrict__ scale,
                                            const float* __restrict__ bias,
                                            unsigned short* __restrict__ h0) {
    int id = blockIdx.x * 256 + threadIdx.x;
    int d = id & (D_DIM - 1);
    h0[id] = f2bf(x[id] * scale[d] + bias[d]);
}

// ---- 3. GEMM: Zt[c][b] = swish(W@h0 + wb). 32(C)x256(N)/block -> 1563 blocks
// (grid was the occupancy limiter at 64-row tiles). Pipelined: W reg-prefetch
// -> convert -> dbuf LDS, 1 barrier/step (BK=64). B fragments direct from
// global (L2-resident h0), prefetched one ksub ahead into registers.
#define AST 72
__global__ __launch_bounds__(256, 4) void k_gemm(const float* __restrict__ W,
                                                 const float* __restrict__ wb,
                                                 const unsigned short* __restrict__ h0,
                                                 unsigned short* __restrict__ Zt) {
    __shared__ unsigned short As[2][32 * AST];
    const int t = threadIdx.x;
    const int c0 = blockIdx.x * 32;
    const int w = t >> 6, lane = t & 63;
    const int m = lane & 15, g = lane >> 4;
    const int arow = t >> 3, aseg = t & 7;      // staging: row 0..31, 8 fp32 seg

    const int cA = c0 + arow;
    const bool aval = (cA < C_DIM);
    const float* wsrc = &W[(size_t)cA * D_DIM + aseg * 8];
    unsigned short* asdst0 = &As[0][arow * AST + aseg * 8];
    unsigned short* asdst1 = &As[1][arow * AST + aseg * 8];
    const unsigned short* bbase = h0 + ((w * 64 + m) * D_DIM + g * 8);

    floatx4 acc[2][4];
#pragma unroll
    for (int i = 0; i < 2; ++i)
#pragma unroll
        for (int j = 0; j < 4; ++j) acc[i][j] = (floatx4)0.f;

    float4 pf0 = make_float4(0.f, 0.f, 0.f, 0.f), pf1 = pf0;
    if (aval) { pf0 = *(const float4*)wsrc; pf1 = *(const float4*)(wsrc + 4); }
    *(uint4*)asdst0 = make_uint4(packbf(pf0.x, pf0.y), packbf(pf0.z, pf0.w),
                                 packbf(pf1.x, pf1.y), packbf(pf1.z, pf1.w));
    __syncthreads();

    short8 bnxt[4];
#pragma unroll
    for (int j = 0; j < 4; ++j)
        bnxt[j] = *(const short8*)(bbase + j * 16 * D_DIM);

    for (int s = 0; s < 16; ++s) {
        if (s < 15 && aval) {
            pf0 = *(const float4*)(wsrc + (s + 1) * 64);
            pf1 = *(const float4*)(wsrc + (s + 1) * 64 + 4);
        }
        const unsigned short* asrd = &As[s & 1][0];
#pragma unroll
        for (int ksub = 0; ksub < 2; ++ksub) {
            short8 bcur[4];
#pragma unroll
            for (int j = 0; j < 4; ++j) bcur[j] = bnxt[j];
            int nk = s * 2 + ksub + 1;
            if (nk < 32) {
                const unsigned short* bp = bbase + (nk >> 1) * 64 + (nk & 1) * 32;
#pragma unroll
                for (int j = 0; j < 4; ++j)
                    bnxt[j] = *(const short8*)(bp + j * 16 * D_DIM);
            }
            short8 af[2];
#pragma unroll
            for (int i = 0; i < 2; ++i)
                af[i] = *(const short8*)&asrd[(i * 16 + m) * AST + ksub * 32 + g * 8];
#pragma unroll
            for (int i = 0; i < 2; ++i)
#pragma unroll
                for (int j = 0; j < 4; ++j)
                    acc[i][j] = __builtin_amdgcn_mfma_f32_16x16x32_bf16(af[i], bcur[j], acc[i][j], 0, 0, 0);
        }
        if (s < 15) {
            unsigned short* dst = ((s + 1) & 1) ? asdst1 : asdst0;
            *(uint4*)dst = make_uint4(packbf(pf0.x, pf0.y), packbf(pf0.z, pf0.w),
                                      packbf(pf1.x, pf1.y), packbf(pf1.z, pf1.w));
            __syncthreads();
        }
    }

    // epilogue: bias + swish, store bf16 to Zt[c][b]
#pragma unroll
    for (int i = 0; i < 2; ++i) {
#pragma unroll
        for (int j = 0; j < 4; ++j) {
            int b = w * 64 + j * 16 + m;
#pragma unroll
            for (int rr = 0; rr < 4; ++rr) {
                int c = c0 + i * 16 + g * 4 + rr;
                if (c < C_DIM) {
                    float x = acc[i][j][rr] + wb[c];
                    float z = x / (1.f + __expf(-x));
                    Zt[(size_t)c * 256 + b] = f2bf(z);
                }
            }
        }
    }
}

// ---- 4. CSR build
__global__ __launch_bounds__(256) void k_count(const int* __restrict__ rows,
                                               int* __restrict__ counts) {
    int id = blockIdx.x * 256 + threadIdx.x;
    if (id < E_TOT) atomicAdd(&counts[rows[id]], 1);
}

__global__ __launch_bounds__(256) void k_scan1(const int* __restrict__ counts,
                                               int* __restrict__ offsets,
                                               int* __restrict__ bsums) {
    __shared__ int sm[256];
    int t = threadIdx.x, i = blockIdx.x * 256 + t;
    int v = (i < C_DIM) ? counts[i] : 0;
    sm[t] = v; __syncthreads();
    for (int off = 1; off < 256; off <<= 1) {
        int x = (t >= off) ? sm[t - off] : 0;
        __syncthreads();
        sm[t] += x;
        __syncthreads();
    }
    if (i < C_DIM) offsets[i] = sm[t] - v;
    if (t == 255) bsums[blockIdx.x] = sm[255];
}

__global__ __launch_bounds__(256) void k_scan2(int* __restrict__ bsums,
                                               int* __restrict__ offsets) {
    __shared__ int sm[256];
    int t = threadIdx.x;
    int v = (t < 196) ? bsums[t] : 0;
    sm[t] = v; __syncthreads();
    for (int off = 1; off < 256; off <<= 1) {
        int x = (t >= off) ? sm[t - off] : 0;
        __syncthreads();
        sm[t] += x;
        __syncthreads();
    }
    if (t < 196) bsums[t] = sm[t] - v;
    if (t == 0) offsets[C_DIM] = sm[255];
}

__global__ __launch_bounds__(256) void k_scan3(const int* __restrict__ bsums,
                                               int* __restrict__ offsets,
                                               int* __restrict__ cursor) {
    int i = blockIdx.x * 256 + threadIdx.x;
    if (i < C_DIM) {
        int off = offsets[i] + bsums[blockIdx.x];
        offsets[i] = off;
        cursor[i] = off;
    }
}

__global__ __launch_bounds__(256) void k_scatter(const int* __restrict__ rows,
                                                 const int* __restrict__ cols,
                                                 const float* __restrict__ vals,
                                                 const float* __restrict__ vec,
                                                 int* __restrict__ cursor,
                                                 int2* __restrict__ edges) {
    int id = blockIdx.x * 256 + threadIdx.x;
    if (id < E_TOT) {
        int gidx = id / NNZ_G;
        float v = vals[id] * vec[gidx];
        int r = rows[id];
        int c = cols[id];
        int pos = atomicAdd(&cursor[r], 1);
        edges[pos] = make_int2(c, __float_as_int(v));
    }
}

// ---- 5. Aggregation + residual. Block = 4 waves = 32 rows (wave: 8 rows seq).
// Per row: 8-edge groups, 2 edges/instruction (lane>>5 picks edge, lane&31 is
// batch-oct, dwordx4 = 16 B/lane) -> 4 gathers in flight/wave. Cross-half
// shfl reduce, residual add, LDS transpose, coalesced 128 B/thread writes.
__global__ __launch_bounds__(256) void k_agg(const unsigned short* __restrict__ Zt,
                                             const int* __restrict__ offsets,
                                             const int2* __restrict__ edges,
                                             float* __restrict__ out) {
    __shared__ float sm[32 * 256];
    const int t = threadIdx.x;
    const int w = t >> 6, lane = t & 63;
    const int r0 = blockIdx.x * 32;
    const int h = lane >> 5;             // edge slot within pair
    const int b8 = lane & 31;            // batch oct: cols b8*8 .. b8*8+7
    const int zoff = b8 * 8;             // shorts

#pragma unroll 1
    for (int k = 0; k < 8; ++k) {
        int lrow = w * 8 + k;
        int r = r0 + lrow;
        if (r >= C_DIM) break;           // wave-uniform
        float a0 = 0.f, a1 = 0.f, a2 = 0.f, a3 = 0.f;
        float a4 = 0.f, a5 = 0.f, a6 = 0.f, a7 = 0.f;
        const int s0 = offsets[r], e0 = offsets[r + 1];
        for (int s = s0; s < e0; s += 8) {
#pragma unroll
            for (int u = 0; u < 4; ++u) {
                int idx = s + u * 2 + h;
                bool ok = idx < e0;
                int2 ed = edges[ok ? idx : s0];
                float v = ok ? __int_as_float(ed.y) : 0.f;
                uint4 gz = *(const uint4*)&Zt[(size_t)ed.x * 256 + zoff];
                a0 += v * bflo(gz.x); a1 += v * bfhi(gz.x);
                a2 += v * bflo(gz.y); a3 += v * bfhi(gz.y);
                a4 += v * bflo(gz.z); a5 += v * bfhi(gz.z);
                a6 += v * bflo(gz.w); a7 += v * bfhi(gz.w);
            }
        }
        a0 += __shfl_xor(a0, 32, 64); a1 += __shfl_xor(a1, 32, 64);
        a2 += __shfl_xor(a2, 32, 64); a3 += __shfl_xor(a3, 32, 64);
        a4 += __shfl_xor(a4, 32, 64); a5 += __shfl_xor(a5, 32, 64);
        a6 += __shfl_xor(a6, 32, 64); a7 += __shfl_xor(a7, 32, 64);
        if (h == 0) {
            uint4 rz = *(const uint4*)&Zt[(size_t)r * 256 + zoff];
            a0 += bflo(rz.x); a1 += bfhi(rz.x);
            a2 += bflo(rz.y); a3 += bfhi(rz.y);
            a4 += bflo(rz.z); a5 += bfhi(rz.z);
            a6 += bflo(rz.w); a7 += bfhi(rz.w);
            float* sp = &sm[lrow * 256 + zoff];
            *(float4*)sp = make_float4(a0, a1, a2, a3);
            *(float4*)(sp + 4) = make_float4(a4, a5, a6, a7);
        }
    }
    __syncthreads();

    // write phase: thread t = batch col, writes out[t][r0 .. r0+rows) contiguous
    int rows = C_DIM - r0; if (rows > 32) rows = 32;
    int nq = rows >> 2;
    float4* op = (float4*)&out[(size_t)t * C_DIM + r0];
#pragma unroll 1
    for (int q = 0; q < nq; ++q) {
        float4 o;
        o.x = sm[(q * 4 + 0) * 256 + t];
        o.y = sm[(q * 4 + 1) * 256 + t];
        o.z = sm[(q * 4 + 2) * 256 + t];
        o.w = sm[(q * 4 + 3) * 256 + t];
        op[q] = o;
    }
}

extern "C" void kernel_launch(void* const* d_in, const int* in_sizes, int n_in,
                              void* d_out, int out_size, void* d_ws, size_t ws_size,
                              hipStream_t stream) {
    (void)in_sizes; (void)n_in; (void)out_size; (void)ws_size;
    const float* x     = (const float*)d_in[0];
    const float* W     = (const float*)d_in[1];
    const float* wb    = (const float*)d_in[2];
    const float* Avals = (const float*)d_in[3];
    const float* vec   = (const float*)d_in[4];
    const int*   Arows = (const int*)d_in[5];
    const int*   Acols = (const int*)d_in[6];
    float* out = (float*)d_out;
    char* ws = (char*)d_ws;

    float* scale = (float*)(ws + O_SB);
    float* bias  = scale + 1024;
    unsigned short* h0 = (unsigned short*)(ws + O_H0);
    unsigned short* Zt = (unsigned short*)(ws + O_ZT);
    int* counts  = (int*)(ws + O_CNT);
    int* offsets = (int*)(ws + O_OFF);
    int* cursor  = (int*)(ws + O_CUR);
    int* bsums   = (int*)(ws + O_BS);
    int2* edges  = (int2*)(ws + O_EDG);

    hipMemsetAsync(counts, 0, C_DIM * sizeof(int), stream);

    k_bnstats<<<4, 256, 0, stream>>>(x, scale, bias);
    k_h0<<<1024, 256, 0, stream>>>(x, scale, bias, h0);
    k_count<<<(E_TOT + 255) / 256, 256, 0, stream>>>(Arows, counts);
    k_gemm<<<(C_DIM + 31) / 32, 256, 0, stream>>>(W, wb, h0, Zt);
    k_scan1<<<196, 256, 0, stream>>>(counts, offsets, bsums);
    k_scan2<<<1, 256, 0, stream>>>(bsums, offsets);
    k_scan3<<<196, 256, 0, stream>>>(bsums, offsets, cursor);
    k_scatter<<<(E_TOT + 255) / 256, 256, 0, stream>>>(Arows, Acols, Avals, vec, cursor, edges);
    k_agg<<<(C_DIM + 31) / 32, 256, 0, stream>>>(Zt, offsets, edges, out);
}